// Round 1
// baseline (588.712 us; speedup 1.0000x reference)
//
#include <hip/hip_runtime.h>
#include <hip/hip_bf16.h>

typedef __hip_bfloat16 bf16;

#define HWH 784   // 28*28
#define NWIN 49

// ---------------------------------------------------------------------------
// Fold fc_w (9x12) into dep_w (256,9,3,3):  W2[oc][c12][k9]
// ---------------------------------------------------------------------------
__global__ __launch_bounds__(256) void fold_w2(const float* __restrict__ fc_w,
                                               const float* __restrict__ dep_w,
                                               float* __restrict__ W2) {
    int idx = blockIdx.x * 256 + threadIdx.x;   // oc*108 + c12*9 + k9
    if (idx >= 256 * 108) return;
    int oc  = idx / 108;
    int r   = idx % 108;
    int c12 = r / 9;
    int k9  = r % 9;
    float s = 0.f;
#pragma unroll
    for (int o = 0; o < 9; ++o)
        s += fc_w[o * 12 + c12] * dep_w[oc * 81 + o * 9 + k9];
    W2[idx] = s;
}

// ---------------------------------------------------------------------------
// QKV 1x1-conv GEMM: qkv[b][o][n] = sum_c W[o][c] * x[b][c][n] + bias[o]
// o in [0,768): 0-255=q (w1), 256-511=k (w2), 512-767=v (w3). Stored bf16.
// Tile 64x64, BK=16, 256 threads, 4x4 micro-tile.
// ---------------------------------------------------------------------------
__global__ __launch_bounds__(256) void gemm_qkv(
    const float* __restrict__ x,
    const float* __restrict__ w1, const float* __restrict__ b1,
    const float* __restrict__ w2, const float* __restrict__ b2,
    const float* __restrict__ w3, const float* __restrict__ b3,
    bf16* __restrict__ qkv) {
    __shared__ float Ws[16][68];   // [k][m], padded row stride 68 (16B-aligned, 2-way max)
    __shared__ float Xs[16][64];   // [k][n]

    const int tid = threadIdx.x;
    const int b   = blockIdx.z;
    const int m0  = blockIdx.y * 64;
    const int n0  = blockIdx.x * 64;

    const float* Wm; const float* bias; int mb;
    if (m0 < 256)      { Wm = w1; bias = b1; mb = m0; }
    else if (m0 < 512) { Wm = w2; bias = b2; mb = m0 - 256; }
    else               { Wm = w3; bias = b3; mb = m0 - 512; }

    const int tn4 = (tid & 15) * 4;
    const int tm4 = (tid >> 4) * 4;
    float acc[4][4] = {};
    const float* xb = x + (size_t)b * (256 * HWH);

    for (int k0 = 0; k0 < 256; k0 += 16) {
#pragma unroll
        for (int e = tid; e < 1024; e += 256) {     // W tile: coalesced over k
            int m = e >> 4, k = e & 15;
            Ws[k][m] = Wm[(mb + m) * 256 + k0 + k];
        }
#pragma unroll
        for (int e = tid; e < 1024; e += 256) {     // X tile: coalesced over n
            int k = e >> 6, n = e & 63;
            int nn = n0 + n;
            Xs[k][n] = (nn < HWH) ? xb[(k0 + k) * HWH + nn] : 0.f;
        }
        __syncthreads();
#pragma unroll
        for (int k = 0; k < 16; ++k) {
            float4 av = *reinterpret_cast<const float4*>(&Ws[k][tm4]);
            float4 bv = *reinterpret_cast<const float4*>(&Xs[k][tn4]);
            float a[4]  = {av.x, av.y, av.z, av.w};
            float bb[4] = {bv.x, bv.y, bv.z, bv.w};
#pragma unroll
            for (int i = 0; i < 4; ++i)
#pragma unroll
                for (int j = 0; j < 4; ++j)
                    acc[i][j] += a[i] * bb[j];
        }
        __syncthreads();
    }

    float bvv[4];
#pragma unroll
    for (int i = 0; i < 4; ++i) bvv[i] = bias[mb + tm4 + i];

    bf16* qb = qkv + (size_t)b * (768 * HWH);
#pragma unroll
    for (int i = 0; i < 4; ++i) {
        int row = m0 + tm4 + i;
#pragma unroll
        for (int j = 0; j < 4; ++j) {
            int col = n0 + tn4 + j;
            if (col < HWH)
                qb[row * HWH + col] = __float2bfloat16(acc[i][j] + bvv[i]);
        }
    }
}

// ---------------------------------------------------------------------------
// Attention collapse: per (b, c) compute the 49 window values.
// Interior windows (i,j in [1,5]): mean of v over the 12x12 patch. Else 0.
// ---------------------------------------------------------------------------
__global__ __launch_bounds__(64) void att_win(const bf16* __restrict__ qkv,
                                              float* __restrict__ attv) {
    __shared__ float vp[HWH];
    const int c = blockIdx.x, b = blockIdx.y, tid = threadIdx.x;
    const bf16* vr = qkv + (size_t)b * (768 * HWH) + (size_t)(512 + c) * HWH;
    for (int i = tid; i < HWH; i += 64) vp[i] = __bfloat162float(vr[i]);
    __syncthreads();
    if (tid < NWIN) {
        int wi = tid / 7, wj = tid % 7;
        float val = 0.f;
        if (wi >= 1 && wi <= 5 && wj >= 1 && wj <= 5) {
            float s = 0.f;
            int r0 = 4 * wi - 4, c0 = 4 * wj - 4;
#pragma unroll
            for (int r = 0; r < 12; ++r)
#pragma unroll
                for (int q = 0; q < 12; ++q)
                    s += vp[(r0 + r) * 28 + c0 + q];
            val = s * (1.0f / 144.0f);
        }
        attv[((size_t)b * 256 + c) * NWIN + tid] = val;
    }
}

// ---------------------------------------------------------------------------
// Fused output: out = rate1 * att + rate2 * conv
// Block per (g, b): 12 input planes (q/k/v at channel hd*64+g) with 1-halo in
// LDS; 4 output channels 4g..4g+3. Each thread: a 4-wide pixel strip.
// ---------------------------------------------------------------------------
__global__ __launch_bounds__(256) void out_fused(
    const bf16* __restrict__ qkv, const float* __restrict__ attv,
    const float* __restrict__ W2, const float* __restrict__ rate1,
    const float* __restrict__ rate2, float* __restrict__ out) {
    __shared__ float plane[12][900];   // 30x30 zero-padded planes
    __shared__ float w2s[4][108];
    __shared__ float attb[4][49];

    const int g = blockIdx.x, b = blockIdx.y, tid = threadIdx.x;
    const bf16* qb = qkv + (size_t)b * (768 * HWH);

    for (int e = tid; e < 432; e += 256) {
        int oc = e / 108, r = e % 108;
        w2s[oc][r] = W2[(4 * g + oc) * 108 + r];
    }
    for (int e = tid; e < 196; e += 256) {
        int oc = e / 49;
        attb[oc][e % 49] = attv[((size_t)b * 256 + 4 * g + oc) * 49 + (e % 49)];
    }
    for (int e = tid; e < 10800; e += 256) {
        int c12 = e / 900, idx = e % 900;
        int yy = idx / 30 - 1, xx = idx % 30 - 1;
        int sec = c12 >> 2, hd = c12 & 3;
        int row = sec * 256 + hd * 64 + g;
        float v = 0.f;
        if (yy >= 0 && yy < 28 && xx >= 0 && xx < 28)
            v = __bfloat162float(qb[row * HWH + yy * 28 + xx]);
        plane[c12][idx] = v;
    }
    __syncthreads();

    if (tid < 196) {
        const float r1 = rate1[0], r2 = rate2[0];
        const int y = tid / 7, x0 = (tid % 7) * 4;
        float acc[4][4] = {};   // [oc][px]
#pragma unroll
        for (int c = 0; c < 12; ++c) {
            float rr[3][6];
#pragma unroll
            for (int dy = 0; dy < 3; ++dy)
#pragma unroll
                for (int j = 0; j < 6; ++j)
                    rr[dy][j] = plane[c][(y + dy) * 30 + x0 + j];
#pragma unroll
            for (int oc = 0; oc < 4; ++oc) {
#pragma unroll
                for (int ky = 0; ky < 3; ++ky)
#pragma unroll
                    for (int kx = 0; kx < 3; ++kx) {
                        float wv = w2s[oc][c * 9 + ky * 3 + kx];
#pragma unroll
                        for (int px = 0; px < 4; ++px)
                            acc[oc][px] += wv * rr[ky][px + kx];
                    }
            }
        }
        const int wi = y >> 2, wj = tid % 7;
#pragma unroll
        for (int oc = 0; oc < 4; ++oc) {
            float av = attb[oc][wi * 7 + wj] * r1;
            float4 o;
            o.x = av + r2 * acc[oc][0];
            o.y = av + r2 * acc[oc][1];
            o.z = av + r2 * acc[oc][2];
            o.w = av + r2 * acc[oc][3];
            *reinterpret_cast<float4*>(
                &out[((size_t)(b * 256 + 4 * g + oc)) * HWH + y * 28 + x0]) = o;
        }
    }
}

// ---------------------------------------------------------------------------
extern "C" void kernel_launch(void* const* d_in, const int* in_sizes, int n_in,
                              void* d_out, int out_size, void* d_ws, size_t ws_size,
                              hipStream_t stream) {
    const float* x     = (const float*)d_in[0];
    const float* w1    = (const float*)d_in[1];
    const float* b1    = (const float*)d_in[2];
    const float* w2    = (const float*)d_in[3];
    const float* b2    = (const float*)d_in[4];
    const float* w3    = (const float*)d_in[5];
    const float* b3    = (const float*)d_in[6];
    const float* fc_w  = (const float*)d_in[7];
    const float* dep_w = (const float*)d_in[8];
    // d_in[9] = rel_height, d_in[10] = rel_width: provably dead (mask collapse)
    const float* rate1 = (const float*)d_in[11];
    const float* rate2 = (const float*)d_in[12];
    float* out = (float*)d_out;

    // workspace layout
    char* wsb = (char*)d_ws;
    bf16*  qkv  = (bf16*)wsb;                        // 64*768*784*2 = 77,070,336 B
    float* attv = (float*)(wsb + 77070336);          // 64*256*49*4  =  3,211,264 B
    float* W2   = (float*)(wsb + 80281600);          // 256*108*4    =    110,592 B

    fold_w2 <<<dim3(108),          dim3(256), 0, stream>>>(fc_w, dep_w, W2);
    gemm_qkv<<<dim3(13, 12, 64),   dim3(256), 0, stream>>>(x, w1, b1, w2, b2, w3, b3, qkv);
    att_win <<<dim3(256, 64),      dim3(64),  0, stream>>>(qkv, attv);
    out_fused<<<dim3(64, 64),      dim3(256), 0, stream>>>(qkv, attv, W2, rate1, rate2, out);
}

// Round 2
// 302.001 us; speedup vs baseline: 1.9494x; 1.9494x over previous
//
#include <hip/hip_runtime.h>
#include <hip/hip_bf16.h>

typedef __hip_bfloat16 bf16;
typedef unsigned int uint;

using frag8 = __attribute__((ext_vector_type(8))) short;   // 8 bf16
using f32x4 = __attribute__((ext_vector_type(4))) float;

#define HWH 784   // 28*28

// ---------------------------------------------------------------------------
// Fold fc_w (9x12) into dep_w (256,9,3,3):  W2[oc][c12][k9]; also biascat.
// ---------------------------------------------------------------------------
__global__ __launch_bounds__(256) void fold_w2(const float* __restrict__ fc_w,
                                               const float* __restrict__ dep_w,
                                               const float* __restrict__ b1,
                                               const float* __restrict__ b2,
                                               const float* __restrict__ b3,
                                               float* __restrict__ W2,
                                               float* __restrict__ biascat) {
    int idx = blockIdx.x * 256 + threadIdx.x;   // oc*108 + c12*9 + k9
    if (idx < 768) {
        const float* bs = idx < 256 ? b1 : (idx < 512 ? b2 : b3);
        biascat[idx] = bs[idx & 255];
    }
    if (idx >= 256 * 108) return;
    int oc  = idx / 108;
    int r   = idx % 108;
    int c12 = r / 9;
    int k9  = r % 9;
    float s = 0.f;
#pragma unroll
    for (int o = 0; o < 9; ++o)
        s += fc_w[o * 12 + c12] * dep_w[oc * 81 + o * 9 + k9];
    W2[idx] = s;
}

// ---------------------------------------------------------------------------
// Weights f32 -> bf16, concatenated [768][256] (q:w1, k:w2, v:w3)
// ---------------------------------------------------------------------------
__global__ __launch_bounds__(256) void wprep(const float* __restrict__ w1,
                                             const float* __restrict__ w2,
                                             const float* __restrict__ w3,
                                             bf16* __restrict__ wbf) {
    int row = blockIdx.x, tid = threadIdx.x;
    const float* src = row < 256 ? w1 : (row < 512 ? w2 : w3);
    wbf[row * 256 + tid] = __float2bfloat16(src[(row & 255) * 256 + tid]);
}

// ---------------------------------------------------------------------------
// x [b][c=256][n=784] f32  ->  xT [b][n=784][c=256] bf16  (32x32 LDS tiles)
// ---------------------------------------------------------------------------
__global__ __launch_bounds__(256) void xpose(const float* __restrict__ x,
                                             bf16* __restrict__ xT) {
    __shared__ float t[32][33];
    const int n0 = blockIdx.x * 32, c0 = blockIdx.y * 32, b = blockIdx.z;
    const int tid = threadIdx.x;
    const float* xb = x + (size_t)b * (256 * HWH);
#pragma unroll
    for (int e = tid; e < 1024; e += 256) {
        int r = e >> 5, col = e & 31;           // r: c-index, col: n-index
        int n = n0 + col;
        t[r][col] = (n < HWH) ? xb[(size_t)(c0 + r) * HWH + n] : 0.f;
    }
    __syncthreads();
#pragma unroll
    for (int e = tid; e < 512; e += 256) {
        int r = e >> 4, cp = (e & 15) * 2;      // r: n-index, cp: c-pair
        int n = n0 + r;
        if (n < HWH) {
            __hip_bfloat162 h;
            h.x = __float2bfloat16(t[cp][r]);
            h.y = __float2bfloat16(t[cp + 1][r]);
            *reinterpret_cast<__hip_bfloat162*>(
                &xT[((size_t)b * HWH + n) * 256 + c0 + cp]) = h;
        }
    }
}

// ---------------------------------------------------------------------------
// MFMA GEMM: qkv[b][m][n] = sum_k wbf[m][k] * xT[b][n][k] + bias[m]
// M=768, N=784 (7 tiles of 128, last partial), K=256. 128x128 tile, BK=32.
// 4 waves, each 64x64 (4x4 of 16x16x32 bf16 MFMA). Fragment-ordered LDS via
// global_load_lds width 16 -> conflict-free ds_read_b128.
// ---------------------------------------------------------------------------
__device__ inline void load_lds16(const bf16* g, short* lds) {
    __builtin_amdgcn_global_load_lds(
        (const __attribute__((address_space(1))) void*)g,
        (__attribute__((address_space(3))) void*)lds, 16, 0, 0);
}

__global__ __launch_bounds__(256) void gemm_mfma(const bf16* __restrict__ wbf,
                                                 const float* __restrict__ biascat,
                                                 const bf16* __restrict__ xT,
                                                 bf16* __restrict__ qkv) {
    __shared__ short lds[8192];                 // A: [0,4096) shorts, B: [4096,8192)

    const int tid  = threadIdx.x;
    const int wave = tid >> 6, lane = tid & 63;
    const int b    = blockIdx.z;
    const int m0   = blockIdx.y * 128;
    const int n0   = blockIdx.x * 128;
    const int mw   = wave & 1, nw = wave >> 1;  // 2x2 wave grid of 64x64 tiles
    const int lrow = lane & 15, lkc = lane >> 4;  // fragment row / k-chunk

    f32x4 acc[4][4] = {};
    const bf16* xb = xT + (size_t)b * (HWH * 256);

    for (int k0 = 0; k0 < 256; k0 += 32) {
#pragma unroll
        for (int i = 0; i < 2; ++i) {
            const int jb = 2 * wave + i;        // fragment-block (16 rows)
            const bf16* ga = wbf + (size_t)(m0 + 16 * jb + lrow) * 256 + k0 + lkc * 8;
            load_lds16(ga, &lds[jb * 512]);
            int n = n0 + 16 * jb + lrow;
            if (n > HWH - 1) n = HWH - 1;       // clamp: OOB cols never stored
            const bf16* gb = xb + (size_t)n * 256 + k0 + lkc * 8;
            load_lds16(gb, &lds[4096 + jb * 512]);
        }
        __syncthreads();

        frag8 af[4], bf_[4];
#pragma unroll
        for (int i = 0; i < 4; ++i)
            af[i] = *reinterpret_cast<const frag8*>(&lds[(4 * mw + i) * 512 + lane * 8]);
#pragma unroll
        for (int j = 0; j < 4; ++j)
            bf_[j] = *reinterpret_cast<const frag8*>(&lds[4096 + (4 * nw + j) * 512 + lane * 8]);
#pragma unroll
        for (int i = 0; i < 4; ++i)
#pragma unroll
            for (int j = 0; j < 4; ++j)
                acc[i][j] = __builtin_amdgcn_mfma_f32_16x16x32_bf16(
                    af[i], bf_[j], acc[i][j], 0, 0, 0);
        __syncthreads();
    }

    // Epilogue: C/D layout col=lane&15 (n), row=(lane>>4)*4+reg (m)
    bf16* qb = qkv + (size_t)b * (768 * HWH);
#pragma unroll
    for (int i = 0; i < 4; ++i) {
        const int row = m0 + mw * 64 + i * 16 + lkc * 4;
#pragma unroll
        for (int j = 0; j < 4; ++j) {
            const int col = n0 + nw * 64 + j * 16 + lrow;
            if (col < HWH) {
#pragma unroll
                for (int r = 0; r < 4; ++r)
                    qb[(size_t)(row + r) * HWH + col] =
                        __float2bfloat16(acc[i][j][r] + biascat[row + r]);
            }
        }
    }
}

// ---------------------------------------------------------------------------
// Fused output: out = rate1 * att + rate2 * conv.
// Block (g, b): 12 conv planes (q/k/v at channel head*64+g) with 1-halo in LDS,
// plus the 4 v-planes (channels 512+4g..+3) for the attention window means.
// ---------------------------------------------------------------------------
__global__ __launch_bounds__(256) void out_fused2(
    const bf16* __restrict__ qkv, const float* __restrict__ W2,
    const float* __restrict__ rate1, const float* __restrict__ rate2,
    float* __restrict__ out) {
    __shared__ float plane[12][900];   // 30x30 zero-border planes
    __shared__ float w2s[4][108];
    __shared__ float attb[4][49];
    __shared__ short vatt[4][784];     // raw bf16 v planes for attention

    const int g = blockIdx.x, b = blockIdx.y, tid = threadIdx.x;
    const bf16* qb = qkv + (size_t)b * (768 * HWH);

    // ---- phase A: LDS fill ----
    for (int e = tid; e < 432; e += 256)
        w2s[e / 108][e % 108] = W2[(4 * g) * 108 + e];
    if (tid < 196) attb[tid / 49][tid % 49] = 0.f;
    for (int e = tid; e < 1392; e += 256) {     // zero borders only
        int c12 = e / 116, u = e % 116, idx;
        if (u < 30)      idx = u;                       // top row
        else if (u < 60) idx = 870 + (u - 30);          // bottom row
        else { int v = u - 60; idx = ((v >> 1) + 1) * 30 + (v & 1) * 29; }
        plane[c12][idx] = 0.f;
    }
    for (int e = tid; e < 4704; e += 256) {     // 12 planes, uint (2 bf16) loads
        int c12 = e / 392, u = e % 392;
        int p = u * 2, y = p / 28, xx = p % 28;
        int sec = c12 >> 2, head = c12 & 3;
        const uint* src = (const uint*)(qb + (size_t)(sec * 256 + head * 64 + g) * HWH);
        uint w = src[u];
        float2 f = __bfloat1622float2(*(const __hip_bfloat162*)&w);
        plane[c12][(y + 1) * 30 + xx + 1] = f.x;
        plane[c12][(y + 1) * 30 + xx + 2] = f.y;
    }
    for (int e = tid; e < 392; e += 256) {      // 4 v planes, uint4 loads
        int oc = e / 98, u = e % 98;
        const uint4* src = (const uint4*)(qb + (size_t)(512 + 4 * g + oc) * HWH);
        reinterpret_cast<uint4*>(&vatt[oc][0])[u] = src[u];
    }
    __syncthreads();

    // ---- phase B: attention window means (interior windows only) ----
    if (tid < 100) {
        int oc = tid / 25, w = tid % 25;
        int wi = w / 5 + 1, wj = w % 5 + 1;
        int r0 = 4 * wi - 4, c0 = 4 * wj - 4;
        float s = 0.f;
#pragma unroll
        for (int r = 0; r < 12; ++r) {
            const __hip_bfloat162* pv =
                (const __hip_bfloat162*)&vatt[oc][(r0 + r) * 28 + c0];
#pragma unroll
            for (int q = 0; q < 6; ++q) {
                float2 f = __bfloat1622float2(pv[q]);
                s += f.x + f.y;
            }
        }
        attb[oc][wi * 7 + wj] = s * (1.0f / 144.0f);
    }

    // ---- phase C: conv, 4-pixel strips on threads 0..195 ----
    float acc[4][4] = {};   // [oc][px]
    const int y = tid / 7, x0 = (tid % 7) * 4;
    if (tid < 196) {
#pragma unroll
        for (int c = 0; c < 12; ++c) {
            float rr[3][6];
#pragma unroll
            for (int dy = 0; dy < 3; ++dy)
#pragma unroll
                for (int j = 0; j < 6; ++j)
                    rr[dy][j] = plane[c][(y + dy) * 30 + x0 + j];
#pragma unroll
            for (int oc = 0; oc < 4; ++oc)
#pragma unroll
                for (int ky = 0; ky < 3; ++ky)
#pragma unroll
                    for (int kx = 0; kx < 3; ++kx) {
                        float wv = w2s[oc][c * 9 + ky * 3 + kx];
#pragma unroll
                        for (int px = 0; px < 4; ++px)
                            acc[oc][px] += wv * rr[ky][px + kx];
                    }
        }
    }
    __syncthreads();

    // ---- phase D: combine + store ----
    if (tid < 196) {
        const float r1 = rate1[0], r2 = rate2[0];
        const int wi = y >> 2, wj = tid % 7;
#pragma unroll
        for (int oc = 0; oc < 4; ++oc) {
            float av = attb[oc][wi * 7 + wj] * r1;
            float4 o;
            o.x = av + r2 * acc[oc][0];
            o.y = av + r2 * acc[oc][1];
            o.z = av + r2 * acc[oc][2];
            o.w = av + r2 * acc[oc][3];
            *reinterpret_cast<float4*>(
                &out[((size_t)(b * 256 + 4 * g + oc)) * HWH + y * 28 + x0]) = o;
        }
    }
}

// ---------------------------------------------------------------------------
extern "C" void kernel_launch(void* const* d_in, const int* in_sizes, int n_in,
                              void* d_out, int out_size, void* d_ws, size_t ws_size,
                              hipStream_t stream) {
    const float* x     = (const float*)d_in[0];
    const float* w1    = (const float*)d_in[1];
    const float* b1    = (const float*)d_in[2];
    const float* w2    = (const float*)d_in[3];
    const float* b2    = (const float*)d_in[4];
    const float* w3    = (const float*)d_in[5];
    const float* b3    = (const float*)d_in[6];
    const float* fc_w  = (const float*)d_in[7];
    const float* dep_w = (const float*)d_in[8];
    // d_in[9]/d_in[10] = rel_height/rel_width: provably dead (mask collapse)
    const float* rate1 = (const float*)d_in[11];
    const float* rate2 = (const float*)d_in[12];
    float* out = (float*)d_out;

    // workspace layout (all 16B-aligned)
    char* wsb = (char*)d_ws;
    bf16*  qkv     = (bf16*)wsb;                         // 64*768*784*2 = 77,070,336
    bf16*  xT      = (bf16*)(wsb + 77070336);            // 64*784*256*2 = 25,690,112
    bf16*  wbf     = (bf16*)(wsb + 102760448);           // 768*256*2    =    393,216
    float* W2      = (float*)(wsb + 103153664);          // 256*108*4    =    110,592
    float* biascat = (float*)(wsb + 103264256);          // 768*4        =      3,072

    fold_w2  <<<dim3(108),        dim3(256), 0, stream>>>(fc_w, dep_w, b1, b2, b3, W2, biascat);
    wprep    <<<dim3(768),        dim3(256), 0, stream>>>(w1, w2, w3, wbf);
    xpose    <<<dim3(25, 8, 64),  dim3(256), 0, stream>>>(x, xT);
    gemm_mfma<<<dim3(7, 6, 64),   dim3(256), 0, stream>>>(wbf, biascat, xT, qkv);
    out_fused2<<<dim3(64, 64),    dim3(256), 0, stream>>>(qkv, W2, rate1, rate2, out);
}

// Round 4
// 263.005 us; speedup vs baseline: 2.2384x; 1.1483x over previous
//
#include <hip/hip_runtime.h>
#include <hip/hip_bf16.h>

typedef __hip_bfloat16 bf16;
typedef unsigned int uint;

using frag8 = __attribute__((ext_vector_type(8))) short;   // 8 bf16
using f32x4 = __attribute__((ext_vector_type(4))) float;

#define HWH 784   // 28*28

// ---------------------------------------------------------------------------
// Fold fc_w (9x12) into dep_w (256,9,3,3):  W2[oc][c12][k9]; also biascat.
// ---------------------------------------------------------------------------
__global__ __launch_bounds__(256) void fold_w2(const float* __restrict__ fc_w,
                                               const float* __restrict__ dep_w,
                                               const float* __restrict__ b1,
                                               const float* __restrict__ b2,
                                               const float* __restrict__ b3,
                                               float* __restrict__ W2,
                                               float* __restrict__ biascat) {
    int idx = blockIdx.x * 256 + threadIdx.x;   // oc*108 + c12*9 + k9
    if (idx < 768) {
        const float* bs = idx < 256 ? b1 : (idx < 512 ? b2 : b3);
        biascat[idx] = bs[idx & 255];
    }
    if (idx >= 256 * 108) return;
    int oc  = idx / 108;
    int r   = idx % 108;
    int c12 = r / 9;
    int k9  = r % 9;
    float s = 0.f;
#pragma unroll
    for (int o = 0; o < 9; ++o)
        s += fc_w[o * 12 + c12] * dep_w[oc * 81 + o * 9 + k9];
    W2[idx] = s;
}

// ---------------------------------------------------------------------------
// Weights f32 -> bf16, concatenated [768][256] (q:w1, k:w2, v:w3)
// ---------------------------------------------------------------------------
__global__ __launch_bounds__(256) void wprep(const float* __restrict__ w1,
                                             const float* __restrict__ w2,
                                             const float* __restrict__ w3,
                                             bf16* __restrict__ wbf) {
    int row = blockIdx.x, tid = threadIdx.x;
    const float* src = row < 256 ? w1 : (row < 512 ? w2 : w3);
    wbf[row * 256 + tid] = __float2bfloat16(src[(row & 255) * 256 + tid]);
}

// ---------------------------------------------------------------------------
// x [b][c=256][n=784] f32  ->  xT [b][n=784][c=256] bf16  (32x32 LDS tiles)
// ---------------------------------------------------------------------------
__global__ __launch_bounds__(256) void xpose(const float* __restrict__ x,
                                             bf16* __restrict__ xT) {
    __shared__ float t[32][33];
    const int n0 = blockIdx.x * 32, c0 = blockIdx.y * 32, b = blockIdx.z;
    const int tid = threadIdx.x;
    const float* xb = x + (size_t)b * (256 * HWH);
#pragma unroll
    for (int e = tid; e < 1024; e += 256) {
        int r = e >> 5, col = e & 31;           // r: c-index, col: n-index
        int n = n0 + col;
        t[r][col] = (n < HWH) ? xb[(size_t)(c0 + r) * HWH + n] : 0.f;
    }
    __syncthreads();
#pragma unroll
    for (int e = tid; e < 512; e += 256) {
        int r = e >> 4, cp = (e & 15) * 2;      // r: n-index, cp: c-pair
        int n = n0 + r;
        if (n < HWH) {
            __hip_bfloat162 h;
            h.x = __float2bfloat16(t[cp][r]);
            h.y = __float2bfloat16(t[cp + 1][r]);
            *reinterpret_cast<__hip_bfloat162*>(
                &xT[((size_t)b * HWH + n) * 256 + c0 + cp]) = h;
        }
    }
}

// ---------------------------------------------------------------------------
// MFMA GEMM: perm[b][g][t][n] = sum_k wbf[m][k] * xT[b][n][k] + bias[m]
// where m -> sec=m/256, ch=m%256, g=ch%64, head=ch/64, t=sec*4+head.
// M=768, N=784 (7 tiles of 128, last partial), K=256. 128x128 tile, BK=32.
// 4 waves, each 64x64 (4x4 of 16x16x32 bf16 MFMA). Fragment-ordered LDS via
// global_load_lds width 16 -> conflict-free ds_read_b128.
// ---------------------------------------------------------------------------
__device__ inline void load_lds16(const bf16* g, short* lds) {
    __builtin_amdgcn_global_load_lds(
        (const __attribute__((address_space(1))) void*)g,
        (__attribute__((address_space(3))) void*)lds, 16, 0, 0);
}

__global__ __launch_bounds__(256) void gemm_mfma(const bf16* __restrict__ wbf,
                                                 const float* __restrict__ biascat,
                                                 const bf16* __restrict__ xT,
                                                 bf16* __restrict__ perm) {
    __shared__ short lds[8192];                 // A: [0,4096) shorts, B: [4096,8192)

    const int tid  = threadIdx.x;
    const int wave = tid >> 6, lane = tid & 63;
    const int b    = blockIdx.z;
    const int m0   = blockIdx.y * 128;
    const int n0   = blockIdx.x * 128;
    const int mw   = wave & 1, nw = wave >> 1;  // 2x2 wave grid of 64x64 tiles
    const int lrow = lane & 15, lkc = lane >> 4;  // fragment row / k-chunk

    f32x4 acc[4][4] = {};
    const bf16* xb = xT + (size_t)b * (HWH * 256);

    for (int k0 = 0; k0 < 256; k0 += 32) {
#pragma unroll
        for (int i = 0; i < 2; ++i) {
            const int jb = 2 * wave + i;        // fragment-block (16 rows)
            const bf16* ga = wbf + (size_t)(m0 + 16 * jb + lrow) * 256 + k0 + lkc * 8;
            load_lds16(ga, &lds[jb * 512]);
            int n = n0 + 16 * jb + lrow;
            if (n > HWH - 1) n = HWH - 1;       // clamp: OOB cols never stored
            const bf16* gb = xb + (size_t)n * 256 + k0 + lkc * 8;
            load_lds16(gb, &lds[4096 + jb * 512]);
        }
        __syncthreads();

        frag8 af[4], bf_[4];
#pragma unroll
        for (int i = 0; i < 4; ++i)
            af[i] = *reinterpret_cast<const frag8*>(&lds[(4 * mw + i) * 512 + lane * 8]);
#pragma unroll
        for (int j = 0; j < 4; ++j)
            bf_[j] = *reinterpret_cast<const frag8*>(&lds[4096 + (4 * nw + j) * 512 + lane * 8]);
#pragma unroll
        for (int i = 0; i < 4; ++i)
#pragma unroll
            for (int j = 0; j < 4; ++j)
                acc[i][j] = __builtin_amdgcn_mfma_f32_16x16x32_bf16(
                    af[i], bf_[j], acc[i][j], 0, 0, 0);
        __syncthreads();
    }

    // Epilogue: C/D layout col=lane&15 (n), row=(lane>>4)*4+reg (m)
#pragma unroll
    for (int i = 0; i < 4; ++i) {
        const int rowb = m0 + mw * 64 + i * 16 + lkc * 4;
        bf16* dsts[4]; float bias4[4];
#pragma unroll
        for (int r = 0; r < 4; ++r) {
            const int m = rowb + r;
            const int sec = m >> 8, ch = m & 255;
            dsts[r] = perm + (((size_t)b * 64 + (ch & 63)) * 12 + sec * 4 + (ch >> 6)) * HWH;
            bias4[r] = biascat[m];
        }
#pragma unroll
        for (int j = 0; j < 4; ++j) {
            const int col = n0 + nw * 64 + j * 16 + lrow;
            if (col < HWH) {
#pragma unroll
                for (int r = 0; r < 4; ++r)
                    dsts[r][col] = __float2bfloat16(acc[i][j][r] + bias4[r]);
            }
        }
    }
}

// ---------------------------------------------------------------------------
// Fused output: out = rate1 * att + rate2 * conv.
// Block (g, b): 12 conv planes are CONTIGUOUS in perm -> flat uint4 copy into
// padded f32 LDS (pitch 31 -> conflict-free column-major lane access).
// 4 v-planes (channels 4g..4g+3) gathered for the attention window means.
// ---------------------------------------------------------------------------
__global__ __launch_bounds__(256) void out_fused3(
    const bf16* __restrict__ perm, const float* __restrict__ W2,
    const float* __restrict__ rate1, const float* __restrict__ rate2,
    float* __restrict__ out) {
    __shared__ float plane[12][930];            // 30 rows x pitch 31, 1-halo
    __shared__ float w2s2[4][12][12];           // [oc][c][k], k padded 9->12
    __shared__ float attb[4][49];
    __shared__ __align__(16) short vatt[4][784];

    const int g = blockIdx.x, b = blockIdx.y, tid = threadIdx.x;

    // ---- phase A: LDS fill ----
    for (int e = tid; e < 576; e += 256) {      // weights, float4-friendly layout
        int oc = e / 144, rem = e % 144, c = rem / 12, k = rem % 12;
        w2s2[oc][c][k] = (k < 9) ? W2[(4 * g + oc) * 108 + c * 9 + k] : 0.f;
    }
    if (tid < 196) attb[tid / 49][tid % 49] = 0.f;
    for (int e = tid; e < 1392; e += 256) {     // zero halo borders only
        int c12 = e / 116, u = e % 116, idx;
        if (u < 30)      idx = u;                        // top row
        else if (u < 60) idx = 29 * 31 + (u - 30);       // bottom row
        else { int v = u - 60; idx = ((v >> 1) + 1) * 31 + (v & 1) * 29; }
        plane[c12][idx] = 0.f;
    }
    {   // 12 conv planes: one contiguous 18,816 B streak of uint4
        const uint4* src = (const uint4*)(perm + ((size_t)b * 64 + g) * 12 * HWH);
        for (int e = tid; e < 1176; e += 256) {
            int c12 = e / 98, u = e % 98;
            uint4 q = src[e];
            uint uu[4] = {q.x, q.y, q.z, q.w};
            int p = u * 8, y = p / 28, x = p - y * 28;
            int ry = y + 1, cx = x + 1;
            float* pl = &plane[c12][0];
#pragma unroll
            for (int t4 = 0; t4 < 4; ++t4) {
                float2 f = __bfloat1622float2(*(const __hip_bfloat162*)&uu[t4]);
                pl[ry * 31 + cx] = f.x; if (++cx == 29) { cx = 1; ++ry; }
                pl[ry * 31 + cx] = f.y; if (++cx == 29) { cx = 1; ++ry; }
            }
        }
    }
    for (int e = tid; e < 392; e += 256) {      // 4 v-planes for attention
        int oc = e / 98, u = e % 98;
        int c = 4 * g + oc;                     // v channel -> perm[b][c%64][8+c/64]
        const uint4* src = (const uint4*)(
            perm + (((size_t)b * 64 + (c & 63)) * 12 + 8 + (c >> 6)) * HWH);
        reinterpret_cast<uint4*>(&vatt[oc][0])[u] = src[u];
    }
    __syncthreads();

    // ---- phase B: attention window means (interior windows only) ----
    if (tid < 100) {
        int oc = tid / 25, w = tid % 25;
        int wi = w / 5 + 1, wj = w % 5 + 1;
        int r0 = 4 * wi - 4, c0 = 4 * wj - 4;
        float s = 0.f;
#pragma unroll
        for (int r = 0; r < 12; ++r) {
            const __hip_bfloat162* pv =
                (const __hip_bfloat162*)&vatt[oc][(r0 + r) * 28 + c0];
#pragma unroll
            for (int q = 0; q < 6; ++q) {
                float2 f = __bfloat1622float2(pv[q]);
                s += f.x + f.y;
            }
        }
        attb[oc][wi * 7 + wj] = s * (1.0f / 144.0f);
    }

    // ---- phase C: conv. Lanes consecutive in y -> LDS stride 31 (no conflicts)
    float acc[4][4] = {};   // [oc][px]
    const int y = tid % 28, xs = tid / 28, x0 = xs * 4;
    if (tid < 196) {
#pragma unroll
        for (int c = 0; c < 12; ++c) {
            float rr[3][6];
#pragma unroll
            for (int dy = 0; dy < 3; ++dy)
#pragma unroll
                for (int j = 0; j < 6; ++j)
                    rr[dy][j] = plane[c][(y + dy) * 31 + x0 + j];
#pragma unroll
            for (int oc = 0; oc < 4; ++oc) {
                const float4* wr = reinterpret_cast<const float4*>(&w2s2[oc][c][0]);
                float4 wa = wr[0], wb = wr[1], wc = wr[2];
                const float wk[9] = {wa.x, wa.y, wa.z, wa.w, wb.x, wb.y, wb.z, wb.w, wc.x};
#pragma unroll
                for (int ky = 0; ky < 3; ++ky)
#pragma unroll
                    for (int kx = 0; kx < 3; ++kx) {
                        float wv = wk[ky * 3 + kx];
#pragma unroll
                        for (int px = 0; px < 4; ++px)
                            acc[oc][px] += wv * rr[ky][px + kx];
                    }
            }
        }
    }
    __syncthreads();

    // ---- phase D: combine + store ----
    if (tid < 196) {
        const float r1 = rate1[0], r2 = rate2[0];
        const int wi = y >> 2, wj = xs;
#pragma unroll
        for (int oc = 0; oc < 4; ++oc) {
            float av = attb[oc][wi * 7 + wj] * r1;
            float4 o;
            o.x = av + r2 * acc[oc][0];
            o.y = av + r2 * acc[oc][1];
            o.z = av + r2 * acc[oc][2];
            o.w = av + r2 * acc[oc][3];
            *reinterpret_cast<float4*>(
                &out[((size_t)(b * 256 + 4 * g + oc)) * HWH + y * 28 + x0]) = o;
        }
    }
}

// ---------------------------------------------------------------------------
extern "C" void kernel_launch(void* const* d_in, const int* in_sizes, int n_in,
                              void* d_out, int out_size, void* d_ws, size_t ws_size,
                              hipStream_t stream) {
    const float* x     = (const float*)d_in[0];
    const float* w1    = (const float*)d_in[1];
    const float* b1    = (const float*)d_in[2];
    const float* w2    = (const float*)d_in[3];
    const float* b2    = (const float*)d_in[4];
    const float* w3    = (const float*)d_in[5];
    const float* b3    = (const float*)d_in[6];
    const float* fc_w  = (const float*)d_in[7];
    const float* dep_w = (const float*)d_in[8];
    // d_in[9]/d_in[10] = rel_height/rel_width: provably dead (mask collapse)
    const float* rate1 = (const float*)d_in[11];
    const float* rate2 = (const float*)d_in[12];
    float* out = (float*)d_out;

    // workspace layout (all 16B-aligned). perm = 64*64*12*784 ELEMENTS
    // = 38,535,168 elts * 2 B = 77,070,336 BYTES (R3 bug: used elt count as bytes)
    char* wsb = (char*)d_ws;
    bf16*  perm    = (bf16*)wsb;                         // 77,070,336 B
    bf16*  xT      = (bf16*)(wsb + 77070336);            // 64*784*256*2 = 25,690,112 B
    bf16*  wbf     = (bf16*)(wsb + 102760448);           // 768*256*2    =    393,216 B
    float* W2      = (float*)(wsb + 103153664);          // 256*108*4    =    110,592 B
    float* biascat = (float*)(wsb + 103264256);          // 768*4        =      3,072 B

    fold_w2  <<<dim3(108),        dim3(256), 0, stream>>>(fc_w, dep_w, b1, b2, b3, W2, biascat);
    wprep    <<<dim3(768),        dim3(256), 0, stream>>>(w1, w2, w3, wbf);
    xpose    <<<dim3(25, 8, 64),  dim3(256), 0, stream>>>(x, xT);
    gemm_mfma<<<dim3(7, 6, 64),   dim3(256), 0, stream>>>(wbf, biascat, xT, perm);
    out_fused3<<<dim3(64, 64),    dim3(256), 0, stream>>>(perm, W2, rate1, rate2, out);
}